// Round 13
// baseline (52.856 us; speedup 1.0000x reference)
//
#include <hip/hip_runtime.h>

#define WINDOW 48
#define RES 50
#define PRED 96
#define BATCH 2048
#define KTOT 4800
#define KPAD 5120
#define KTRUNC 12
#define KS 10
#define KRB 512       // k per wave = 16 steps of 32

typedef __attribute__((ext_vector_type(8))) short short8v;   // 8 bf16
typedef __attribute__((ext_vector_type(4))) float f32x4;

// ws float offsets
#define OFF_DK 0          // Dk[16][50]            800
#define OFF_WT 800        // Wt[50][96]            4800  -> 5600
#define OFF_KB 5600       // ushort Kb[64][5120]   163840 floats -> 169440 (16B-aligned)
#define OFF_LP 169440     // Lp[10][2048][64]      1310720 -> 1480160
#define OFF_L  1480160    // L[2048][64]           131072 -> 1611232 floats (6.4 MB)

__device__ __forceinline__ float ipow(float b, int n) {
    float r = 1.f, p = b;
    while (n) { if (n & 1) r *= p; p *= p; n >>= 1; }
    return r;
}

// Setup: Dk, Wt, Kb[c][k] = bf16(d_c^(99-j) * M[c][w]), M inline.
__global__ __launch_bounds__(256) void k0(const float* __restrict__ W_lin,
                                          const float* __restrict__ W_in,
                                          const float* __restrict__ d,
                                          const float* __restrict__ W_out,
                                          float* __restrict__ ws) {
    unsigned f = blockIdx.x * 256 + threadIdx.x;
    if (f < 800) {                        // Dk[k][r] = d_r^(100k)
        int k = f / RES, r = f % RES;
        ws[OFF_DK + f] = ipow(ipow(d[r], 100), k);
    } else if (f < 5600) {                // Wt[r][o] = W_out[o][r]
        int e = f - 800;
        int r = e / PRED, o = e % PRED;
        ws[OFF_WT + e] = W_out[o * RES + r];
    }
    if (f < 64u * KPAD) {                 // Kb
        int c = f / KPAD, k = f - (f / KPAD) * KPAD;
        float val = 0.f;
        if (c < RES && k < KTOT) {
            int j = k / WINDOW, w = k - j * WINDOW;
            float m = 0.f;
            for (int v = 0; v < WINDOW; ++v)
                m = fmaf(W_in[c * WINDOW + v], W_lin[v * WINDOW + w], m);
            val = ipow(d[c], 99 - j) * m;
        }
        unsigned u = __builtin_bit_cast(unsigned, val);
        ((unsigned short*)(ws + OFF_KB))[f] =
            (unsigned short)((u + 0x7FFFu + ((u >> 16) & 1u)) >> 16);
    }
}

// One WAVE per block: (mt, s) -> 16 rows x 512 k, 16 steps of 32-k.
// Software-pipelined loop, 2 register sets, opaque trip count (no full hoist).
// A-steps with global step index >= 150 (k>=4800) read x[0..] and hit Kb zeros.
__global__ __launch_bounds__(64, 4) void k1m(const float* __restrict__ x,
                                             const float* __restrict__ ws,
                                             float* __restrict__ lp) {
    const unsigned short* Kb = (const unsigned short*)(ws + OFF_KB);
    int bid = blockIdx.x;
    int mt = bid / KS, s = bid - mt * KS;
    int b0 = mt * 16;
    int l = threadIdx.x & 63;
    int row16 = l & 15, kq = l >> 4;
    int s16 = s * 16;

    const float* ap = x + (size_t)(b0 + row16) * KTOT + s * KRB + kq * 8;
    const unsigned short* bp = Kb + (size_t)row16 * KPAD + s * KRB + kq * 8;

    f32x4 acc0 = (f32x4)(0.f), acc1 = (f32x4)(0.f), acc2 = (f32x4)(0.f), acc3 = (f32x4)(0.f);

    auto loadA = [&](int stp, f32x4& A0, f32x4& A1) {
        const float* p = (s16 + stp < 150) ? (ap + stp * 32) : x;   // clamp OOB
        A0 = *(const f32x4*)p;
        A1 = *(const f32x4*)(p + 4);
    };
    auto loadB = [&](int stp, short8v& B0, short8v& B1, short8v& B2, short8v& B3) {
        const unsigned short* p = bp + stp * 32;
        B0 = *(const short8v*)p;
        B1 = *(const short8v*)(p + 16 * KPAD);
        B2 = *(const short8v*)(p + 32 * KPAD);
        B3 = *(const short8v*)(p + 48 * KPAD);
    };
    auto compute = [&](f32x4 A0, f32x4 A1, short8v B0, short8v B1, short8v B2, short8v B3) {
        short8v ahi, alo;
#pragma unroll
        for (int m = 0; m < 8; ++m) {
            float v = (m < 4) ? A0[m] : A1[m - 4];
            unsigned u = __builtin_bit_cast(unsigned, v);
            unsigned hb = (u + 0x7FFFu + ((u >> 16) & 1u)) & 0xFFFF0000u;
            ahi[m] = (short)(hb >> 16);
            float r = v - __builtin_bit_cast(float, hb);
            unsigned u2 = __builtin_bit_cast(unsigned, r);
            alo[m] = (short)((u2 + 0x7FFFu + ((u2 >> 16) & 1u)) >> 16);
        }
        acc0 = __builtin_amdgcn_mfma_f32_16x16x32_bf16(ahi, B0, acc0, 0, 0, 0);
        acc0 = __builtin_amdgcn_mfma_f32_16x16x32_bf16(alo, B0, acc0, 0, 0, 0);
        acc1 = __builtin_amdgcn_mfma_f32_16x16x32_bf16(ahi, B1, acc1, 0, 0, 0);
        acc1 = __builtin_amdgcn_mfma_f32_16x16x32_bf16(alo, B1, acc1, 0, 0, 0);
        acc2 = __builtin_amdgcn_mfma_f32_16x16x32_bf16(ahi, B2, acc2, 0, 0, 0);
        acc2 = __builtin_amdgcn_mfma_f32_16x16x32_bf16(alo, B2, acc2, 0, 0, 0);
        acc3 = __builtin_amdgcn_mfma_f32_16x16x32_bf16(ahi, B3, acc3, 0, 0, 0);
        acc3 = __builtin_amdgcn_mfma_f32_16x16x32_bf16(alo, B3, acc3, 0, 0, 0);
    };

    f32x4 a0c, a1c, a0n, a1n;
    short8v b0c, b1c, b2c, b3c, b0n, b1n, b2n, b3n;

    loadA(0, a0c, a1c);
    loadB(0, b0c, b1c, b2c, b3c);

    int n8 = 8;
    asm volatile("" : "+s"(n8));          // opaque trip count: keep a real loop
    for (int ii = 0; ii < n8; ++ii) {
        int st1 = 2 * ii + 1, st2 = 2 * ii + 2;
        loadA(st1, a0n, a1n);
        loadB(st1, b0n, b1n, b2n, b3n);
        compute(a0c, a1c, b0c, b1c, b2c, b3c);      // step 2ii
        loadA(st2, a0c, a1c);                        // next even (last one unused)
        loadB(st2, b0c, b1c, b2c, b3c);
        compute(a0n, a1n, b0n, b1n, b2n, b3n);      // step 2ii+1
    }

    float* dst = lp + ((size_t)s * BATCH + b0) * 64;
#pragma unroll
    for (int i = 0; i < 4; ++i) {
        int r = kq * 4 + i;
        dst[(size_t)r * 64 + row16]      = acc0[i];
        dst[(size_t)r * 64 + row16 + 16] = acc1[i];
        dst[(size_t)r * 64 + row16 + 32] = acc2[i];
        dst[(size_t)r * 64 + row16 + 48] = acc3[i];
    }
}

// L[b][c] = sum_s Lp[s][b][c]
__global__ __launch_bounds__(256) void k2a(float* __restrict__ ws) {
    int e = blockIdx.x * 256 + threadIdx.x;     // < 32768
    const f32x4* lp4 = (const f32x4*)(ws + OFF_LP);
    f32x4 sum = lp4[e];
#pragma unroll
    for (int sp = 1; sp < KS; ++sp)
        sum += lp4[(size_t)sp * 32768 + e];
    ((f32x4*)(ws + OFF_L))[e] = sum;
}

// s[r] = sum_k Dk[k][r]*L[b-k][r]; out[b][o] = sum_r s[r]*Wt[r][o]
__global__ __launch_bounds__(128) void k2b(const float* __restrict__ ws,
                                           float* __restrict__ out) {
    const float* L  = ws + OFF_L;
    const float* Dk = ws + OFF_DK;
    const float* Wt = ws + OFF_WT;
    __shared__ float s_s[52];
    int b = blockIdx.x;
    int t = threadIdx.x;
    if (t < RES) {
        float acc = 0.f;
#pragma unroll
        for (int k = 0; k < KTRUNC; ++k) {
            int bb = b - k;
            if (bb >= 0) acc = fmaf(Dk[k * RES + t], L[(size_t)bb * 64 + t], acc);
        }
        s_s[t] = acc;
    }
    __syncthreads();
    if (t < PRED) {
        float acc = 0.f;
#pragma unroll 10
        for (int r = 0; r < RES; ++r)
            acc = fmaf(s_s[r], Wt[r * PRED + t], acc);
        out[b * PRED + t] = acc;
    }
}

extern "C" void kernel_launch(void* const* d_in, const int* in_sizes, int n_in,
                              void* d_out, int out_size, void* d_ws, size_t ws_size,
                              hipStream_t stream) {
    const float* x     = (const float*)d_in[0];
    const float* W_lin = (const float*)d_in[1];
    const float* W_in  = (const float*)d_in[2];
    const float* d     = (const float*)d_in[3];
    const float* W_out = (const float*)d_in[4];
    float* out = (float*)d_out;
    float* ws  = (float*)d_ws;
    float* lp  = ws + OFF_LP;

    k0<<<1280, 256, 0, stream>>>(W_lin, W_in, d, W_out, ws);
    // PROBE: k1m launched twice (idempotent). R13_total - C = 2*k1m.
    k1m<<<128 * KS, 64, 0, stream>>>(x, ws, lp);
    k1m<<<128 * KS, 64, 0, stream>>>(x, ws, lp);
    k2a<<<128, 256, 0, stream>>>(ws);
    k2b<<<BATCH, 128, 0, stream>>>(ws, out);
}

// Round 14
// 41.031 us; speedup vs baseline: 1.2882x; 1.2882x over previous
//
#include <hip/hip_runtime.h>

#define WINDOW 48
#define RES 50
#define PRED 96
#define BATCH 2048
#define KTOT 4800
#define KPAD 5120
#define KTRUNC 12
#define KS 30         // k-splits; KRB=160 = 5 steps of 32
#define KRB 160

typedef __attribute__((ext_vector_type(8))) short short8v;   // 8 bf16
typedef __attribute__((ext_vector_type(4))) float f32x4;

// ws float offsets
#define OFF_DK 0          // Dk[16][50]            800
#define OFF_WT 800        // Wt[50][96]            4800  -> 5600
#define OFF_KB 5600       // ushort Kb[64][5120]   163840 floats -> 169440
#define OFF_LP 169440     // Lp[30][2048][50]      3072000 -> 3241440 floats (13 MB)

__device__ __forceinline__ float ipow(float b, int n) {
    float r = 1.f, p = b;
    while (n) { if (n & 1) r *= p; p *= p; n >>= 1; }
    return r;
}

// Setup: Dk, Wt, Kb[c][k] = bf16(d_c^(99-j) * M[c][w]), M inline.
__global__ __launch_bounds__(256) void k0(const float* __restrict__ W_lin,
                                          const float* __restrict__ W_in,
                                          const float* __restrict__ d,
                                          const float* __restrict__ W_out,
                                          float* __restrict__ ws) {
    unsigned f = blockIdx.x * 256 + threadIdx.x;
    if (f < 800) {                        // Dk[k][r] = d_r^(100k)
        int k = f / RES, r = f % RES;
        ws[OFF_DK + f] = ipow(ipow(d[r], 100), k);
    } else if (f < 5600) {                // Wt[r][o] = W_out[o][r]
        int e = f - 800;
        int r = e / PRED, o = e % PRED;
        ws[OFF_WT + e] = W_out[o * RES + r];
    }
    if (f < 64u * KPAD) {                 // Kb
        int c = f / KPAD, k = f - (f / KPAD) * KPAD;
        float val = 0.f;
        if (c < RES && k < KTOT) {
            int j = k / WINDOW, w = k - j * WINDOW;
            float m = 0.f;
            for (int v = 0; v < WINDOW; ++v)
                m = fmaf(W_in[c * WINDOW + v], W_lin[v * WINDOW + w], m);
            val = ipow(d[c], 99 - j) * m;
        }
        unsigned u = __builtin_bit_cast(unsigned, val);
        ((unsigned short*)(ws + OFF_KB))[f] =
            (unsigned short)((u + 0x7FFFu + ((u >> 16) & 1u)) >> 16);
    }
}

#define LOADA(st, A0, A1) { A0 = *(const f32x4*)(ap + (st) * 32); \
                            A1 = *(const f32x4*)(ap + (st) * 32 + 4); }
#define LOADB(st, B0, B1, B2, B3) { const unsigned short* p_ = bp + (st) * 32; \
    B0 = *(const short8v*)p_;                    B1 = *(const short8v*)(p_ + 16 * KPAD); \
    B2 = *(const short8v*)(p_ + 32 * KPAD);      B3 = *(const short8v*)(p_ + 48 * KPAD); }
#define COMPUTE(A0, A1, B0, B1, B2, B3) { \
    short8v ahi, alo; \
    _Pragma("unroll") \
    for (int m_ = 0; m_ < 8; ++m_) { \
        float v_ = (m_ < 4) ? A0[m_] : A1[m_ - 4]; \
        unsigned u_ = __builtin_bit_cast(unsigned, v_); \
        unsigned hb_ = (u_ + 0x7FFFu + ((u_ >> 16) & 1u)) & 0xFFFF0000u; \
        ahi[m_] = (short)(hb_ >> 16); \
        float r_ = v_ - __builtin_bit_cast(float, hb_); \
        unsigned u2_ = __builtin_bit_cast(unsigned, r_); \
        alo[m_] = (short)((u2_ + 0x7FFFu + ((u2_ >> 16) & 1u)) >> 16); \
    } \
    acc0 = __builtin_amdgcn_mfma_f32_16x16x32_bf16(ahi, B0, acc0, 0, 0, 0); \
    acc0 = __builtin_amdgcn_mfma_f32_16x16x32_bf16(alo, B0, acc0, 0, 0, 0); \
    acc1 = __builtin_amdgcn_mfma_f32_16x16x32_bf16(ahi, B1, acc1, 0, 0, 0); \
    acc1 = __builtin_amdgcn_mfma_f32_16x16x32_bf16(alo, B1, acc1, 0, 0, 0); \
    acc2 = __builtin_amdgcn_mfma_f32_16x16x32_bf16(ahi, B2, acc2, 0, 0, 0); \
    acc2 = __builtin_amdgcn_mfma_f32_16x16x32_bf16(alo, B2, acc2, 0, 0, 0); \
    acc3 = __builtin_amdgcn_mfma_f32_16x16x32_bf16(ahi, B3, acc3, 0, 0, 0); \
    acc3 = __builtin_amdgcn_mfma_f32_16x16x32_bf16(alo, B3, acc3, 0, 0, 0); }

// Block = 2 independent waves (no LDS, no barrier). Wave: 16 rows x 160 k
// (5 steps of 32), 3-stage static software pipeline. 3840 waves = 15/CU.
__global__ __launch_bounds__(128, 4) void k1p(const float* __restrict__ x,
                                              const float* __restrict__ ws,
                                              float* __restrict__ lp) {
    const unsigned short* Kb = (const unsigned short*)(ws + OFF_KB);
    int bid = blockIdx.x;                 // 128 mt x 15 sg
    int mt = bid / 15, sg = bid - mt * 15;
    int t = threadIdx.x;
    int w = t >> 6, l = t & 63;
    int s = sg * 2 + w;
    int b0 = mt * 16;
    int row16 = l & 15, kq = l >> 4;
    int kw = s * KRB + kq * 8;

    const float* ap = x + (size_t)(b0 + row16) * KTOT + kw;
    const unsigned short* bp = Kb + (size_t)row16 * KPAD + kw;

    f32x4 acc0 = (f32x4)(0.f), acc1 = (f32x4)(0.f), acc2 = (f32x4)(0.f), acc3 = (f32x4)(0.f);

    f32x4 a0s0, a1s0, a0s1, a1s1, a0s2, a1s2;
    short8v b0s0, b1s0, b2s0, b3s0, b0s1, b1s1, b2s1, b3s1, b0s2, b1s2, b2s2, b3s2;

    LOADA(0, a0s0, a1s0) LOADB(0, b0s0, b1s0, b2s0, b3s0)
    LOADA(1, a0s1, a1s1) LOADB(1, b0s1, b1s1, b2s1, b3s1)
    LOADA(2, a0s2, a1s2) LOADB(2, b0s2, b1s2, b2s2, b3s2)

    COMPUTE(a0s0, a1s0, b0s0, b1s0, b2s0, b3s0)
    LOADA(3, a0s0, a1s0) LOADB(3, b0s0, b1s0, b2s0, b3s0)
    COMPUTE(a0s1, a1s1, b0s1, b1s1, b2s1, b3s1)
    LOADA(4, a0s1, a1s1) LOADB(4, b0s1, b1s1, b2s1, b3s1)
    COMPUTE(a0s2, a1s2, b0s2, b1s2, b2s2, b3s2)
    COMPUTE(a0s0, a1s0, b0s0, b1s0, b2s0, b3s0)
    COMPUTE(a0s1, a1s1, b0s1, b1s1, b2s1, b3s1)

    // write Lp[s][b0+r][c], c<50; coalesced per 16 lanes
    float* dst = lp + ((size_t)s * BATCH + b0) * 50;
#pragma unroll
    for (int i = 0; i < 4; ++i) {
        int r = kq * 4 + i;
        dst[(size_t)r * 50 + row16]      = acc0[i];
        dst[(size_t)r * 50 + row16 + 16] = acc1[i];
        dst[(size_t)r * 50 + row16 + 32] = acc2[i];
        if (row16 < 2) dst[(size_t)r * 50 + row16 + 48] = acc3[i];
    }
}

// Fused: L-sum over splits (rows B0-11..B0+15) -> Dk-Horner -> W_out GEMM.
__global__ __launch_bounds__(256) void k2(const float* __restrict__ ws,
                                          float* __restrict__ out) {
    __shared__ float Ls[27 * 52];
    __shared__ float Ss[16 * 52];
    const float* lp = ws + OFF_LP;
    const float* Dk = ws + OFF_DK;
    const float* Wt = ws + OFF_WT;
    int B0 = blockIdx.x * 16;
    int t = threadIdx.x;

    for (int e = t; e < 27 * 50; e += 256) {
        int lr = e / 50, c = e - lr * 50;
        int bb = B0 - 11 + lr;
        float sum = 0.f;
        if (bb >= 0) {
#pragma unroll
            for (int sp = 0; sp < KS; ++sp)
                sum += lp[((size_t)sp * BATCH + bb) * 50 + c];
        }
        Ls[lr * 52 + c] = sum;
    }
    __syncthreads();

    for (int e = t; e < 16 * 50; e += 256) {
        int i = e / 50, r = e - i * 50;
        float acc = 0.f;
#pragma unroll
        for (int k = 0; k < KTRUNC; ++k)
            acc = fmaf(Dk[k * RES + r], Ls[(11 + i - k) * 52 + r], acc);
        Ss[i * 52 + r] = acc;
    }
    __syncthreads();

    for (int e = t; e < 16 * PRED; e += 256) {
        int i = e / PRED, o = e - i * PRED;
        float acc = 0.f;
#pragma unroll 10
        for (int r = 0; r < RES; ++r)
            acc = fmaf(Ss[i * 52 + r], Wt[r * PRED + o], acc);
        out[(B0 + i) * PRED + o] = acc;
    }
}

extern "C" void kernel_launch(void* const* d_in, const int* in_sizes, int n_in,
                              void* d_out, int out_size, void* d_ws, size_t ws_size,
                              hipStream_t stream) {
    const float* x     = (const float*)d_in[0];
    const float* W_lin = (const float*)d_in[1];
    const float* W_in  = (const float*)d_in[2];
    const float* d     = (const float*)d_in[3];
    const float* W_out = (const float*)d_in[4];
    float* out = (float*)d_out;
    float* ws  = (float*)d_ws;
    float* lp  = ws + OFF_LP;

    k0<<<1280, 256, 0, stream>>>(W_lin, W_in, d, W_out, ws);
    k1p<<<128 * 15, 128, 0, stream>>>(x, ws, lp);
    k2<<<128, 256, 0, stream>>>(ws, out);
}